// Round 1
// baseline (1118.456 us; speedup 1.0000x reference)
//
#include <hip/hip_runtime.h>

// ComplexMultiheadAttention on MI355X (gfx950)
// B=2, L=2048, E=1024, H=16, D=64
// Strategy: split-bf16 (hi/lo, 3-product) MFMA GEMMs for all projections and QK^T
// (near-fp32 accuracy), plain bf16 for P@V. Flash-style online softmax.

#define BB 2
#define LL 2048
#define EE 1024
#define HH 16
#define DD 64
#define BL 4096   // B*L
#define KK 2048   // GEMM K dim (re||im)

typedef __attribute__((ext_vector_type(8))) short bf16x8;
typedef __attribute__((ext_vector_type(4))) float f32x4;

__device__ __forceinline__ unsigned short f2bf(float x) {
    unsigned int u = __builtin_bit_cast(unsigned int, x);
    u += 0x7fff + ((u >> 16) & 1);          // round-to-nearest-even
    return (unsigned short)(u >> 16);
}
__device__ __forceinline__ float bf2f(unsigned short h) {
    unsigned int u = ((unsigned int)h) << 16;
    return __builtin_bit_cast(float, u);
}
__device__ __forceinline__ void cvt_hl(float x, unsigned short &h, unsigned short &l) {
    h = f2bf(x);
    l = f2bf(x - bf2f(h));
}

// ---------------------------------------------------------------------------
// Complex linear: out[m, n] for m in [0,4096), n in [0,2048) (n<1024: real, else imag)
//   X2 = [xr | xi] (K=2048), W2[n<1024] = [Wr | -Wi], W2[n>=1024] = [Wi | Wr]
// MODE 0: Q/K epilogue -> ws[bh][l][128] (re||im per head along last dim)
// MODE 1: V epilogue   -> ws[bh][128][2048] (transposed: feature-major)
// MODE 2: out-proj     -> d_out [2, B, L, E]
// ---------------------------------------------------------------------------
template <int MODE>
__launch_bounds__(256, 2)
__global__ void gemm_cplx(const float* __restrict__ Xr, const float* __restrict__ Xi,
                          const float* __restrict__ Wr, const float* __restrict__ Wi,
                          const float* __restrict__ br, const float* __restrict__ bi,
                          float* __restrict__ out)
{
    __shared__ unsigned short As_hi[128][40];   // pad 32->40: 80B row stride, 2-way banks
    __shared__ unsigned short As_lo[128][40];
    __shared__ unsigned short Bs_hi[128][40];
    __shared__ unsigned short Bs_lo[128][40];

    const int tid  = threadIdx.x;
    const int wave = tid >> 6, lane = tid & 63;
    const int quad = lane >> 4, l16 = lane & 15;
    const int m0 = blockIdx.y * 128, n0 = blockIdx.x * 128;
    const int wm = (wave >> 1) * 64, wn = (wave & 1) * 64;

    f32x4 acc[4][4];
    for (int i = 0; i < 4; i++)
        for (int j = 0; j < 4; j++) acc[i][j] = (f32x4)0.0f;

    const bool ni = (n0 >= EE);
    const int  nb = n0 & (EE - 1);

    for (int k0 = 0; k0 < KK; k0 += 32) {
        const bool ki = (k0 >= EE);
        const int  kb = k0 & (EE - 1);
        const float* Xp = ki ? Xi : Xr;
        const float* Wp = ni ? (ki ? Wr : Wi) : (ki ? Wi : Wr);
        const float sgn = (!ni && ki) ? -1.0f : 1.0f;

        // stage A tile [128][32] fp32 -> hi/lo bf16
        for (int i = 0; i < 4; i++) {
            int f = tid + i * 256;               // 1024 float4
            int row = f >> 3, c4 = (f & 7) << 2;
            float4 v = *(const float4*)(Xp + (m0 + row) * EE + kb + c4);
            ushort4 h, lo;
            cvt_hl(v.x, h.x, lo.x); cvt_hl(v.y, h.y, lo.y);
            cvt_hl(v.z, h.z, lo.z); cvt_hl(v.w, h.w, lo.w);
            *(ushort4*)&As_hi[row][c4] = h;
            *(ushort4*)&As_lo[row][c4] = lo;
        }
        // stage B tile [128][32]
        for (int i = 0; i < 4; i++) {
            int f = tid + i * 256;
            int row = f >> 3, c4 = (f & 7) << 2;
            float4 v = *(const float4*)(Wp + (nb + row) * EE + kb + c4);
            v.x *= sgn; v.y *= sgn; v.z *= sgn; v.w *= sgn;
            ushort4 h, lo;
            cvt_hl(v.x, h.x, lo.x); cvt_hl(v.y, h.y, lo.y);
            cvt_hl(v.z, h.z, lo.z); cvt_hl(v.w, h.w, lo.w);
            *(ushort4*)&Bs_hi[row][c4] = h;
            *(ushort4*)&Bs_lo[row][c4] = lo;
        }
        __syncthreads();

        bf16x8 a_hi[4], a_lo[4], b_hi[4], b_lo[4];
        for (int t = 0; t < 4; t++) {
            int ar = wm + t * 16 + l16;
            a_hi[t] = *(const bf16x8*)&As_hi[ar][quad * 8];
            a_lo[t] = *(const bf16x8*)&As_lo[ar][quad * 8];
            int brow = wn + t * 16 + l16;
            b_hi[t] = *(const bf16x8*)&Bs_hi[brow][quad * 8];
            b_lo[t] = *(const bf16x8*)&Bs_lo[brow][quad * 8];
        }
        for (int i = 0; i < 4; i++)
            for (int j = 0; j < 4; j++) {
                acc[i][j] = __builtin_amdgcn_mfma_f32_16x16x32_bf16(a_hi[i], b_hi[j], acc[i][j], 0, 0, 0);
                acc[i][j] = __builtin_amdgcn_mfma_f32_16x16x32_bf16(a_hi[i], b_lo[j], acc[i][j], 0, 0, 0);
                acc[i][j] = __builtin_amdgcn_mfma_f32_16x16x32_bf16(a_lo[i], b_hi[j], acc[i][j], 0, 0, 0);
            }
        __syncthreads();
    }

    // epilogue: C layout col=lane&15, row=quad*4+reg  [verified m89/m91]
    for (int i = 0; i < 4; i++)
        for (int j = 0; j < 4; j++)
            for (int r = 0; r < 4; r++) {
                int gm = m0 + wm + i * 16 + quad * 4 + r;
                int gn = n0 + wn + j * 16 + l16;
                int ri = gn >> 10, e = gn & 1023;
                float v = acc[i][j][r] + (ri ? bi[e] : br[e]);
                if (MODE == 2) {
                    out[ri * (BL * EE) + gm * EE + e] = v;
                } else {
                    int b = gm >> 11, l = gm & 2047;
                    int h = e >> 6, d = e & 63;
                    if (MODE == 0)
                        out[(((b * HH + h) * LL + l) << 7) + ri * 64 + d] = v;
                    else
                        out[((b * HH + h) * 128 + ri * 64 + d) * LL + l] = v;
                }
            }
}

// ---------------------------------------------------------------------------
// Flash attention per (b,h): q,k in [bh][l][128] fp32, v in [bh][128][2048] fp32
// BQ=128 per block (4 waves x 32 rows), BKV=64 per iteration.
// QK^T with hi/lo split (3-product); softmax fp32; P@V plain bf16.
// ---------------------------------------------------------------------------
__launch_bounds__(256, 2)
__global__ void attn(const float* __restrict__ q_ws, const float* __restrict__ k_ws,
                     const float* __restrict__ v_ws,
                     float* __restrict__ o_r, float* __restrict__ o_i)
{
    __shared__ union ShMem {
        struct { unsigned short qhi[128][72]; unsigned short qlo[128][72]; } q;
        struct { unsigned short khi[64][136]; unsigned short klo[64][136];
                 unsigned short vv[128][72]; } kv;
    } sh;   // 53248 B

    const int tid  = threadIdx.x;
    const int wave = tid >> 6, lane = tid & 63;
    const int quad = lane >> 4, l16 = lane & 15;
    const int q0 = blockIdx.x * 128;
    const int bh = blockIdx.y;

    // ---- load Q fragments into registers (hi/lo), via LDS staging in halves ----
    bf16x8 q_hi[2][4], q_lo[2][4];
    for (int half = 0; half < 2; half++) {
        for (int i = 0; i < 8; i++) {
            int f = tid + i * 256;               // 2048 float4 = 128 rows x 64 cols
            int row = f >> 4, c4 = (f & 15) << 2;
            float4 v = *(const float4*)(q_ws + (bh * LL + q0 + row) * 128 + half * 64 + c4);
            ushort4 h, lo;
            cvt_hl(v.x, h.x, lo.x); cvt_hl(v.y, h.y, lo.y);
            cvt_hl(v.z, h.z, lo.z); cvt_hl(v.w, h.w, lo.w);
            *(ushort4*)&sh.q.qhi[row][c4] = h;
            *(ushort4*)&sh.q.qlo[row][c4] = lo;
        }
        __syncthreads();
        for (int mt = 0; mt < 2; mt++) {
            int r = wave * 32 + mt * 16 + l16;
            for (int ks = 0; ks < 2; ks++) {
                q_hi[mt][half * 2 + ks] = *(const bf16x8*)&sh.q.qhi[r][ks * 32 + quad * 8];
                q_lo[mt][half * 2 + ks] = *(const bf16x8*)&sh.q.qlo[r][ks * 32 + quad * 8];
            }
        }
        __syncthreads();
    }

    f32x4 oacc[2][8];
    for (int i = 0; i < 2; i++)
        for (int j = 0; j < 8; j++) oacc[i][j] = (f32x4)0.0f;
    float m_st[2][4], l_st[2][4];
    for (int i = 0; i < 2; i++)
        for (int r = 0; r < 4; r++) { m_st[i][r] = -INFINITY; l_st[i][r] = 0.0f; }

    const float scale = 0.125f;  // 1/sqrt(64)

    for (int kv0 = 0; kv0 < LL; kv0 += 64) {
        // ---- stage K [64][128] hi/lo and V [128][64] plain ----
        for (int i = 0; i < 8; i++) {
            int f = tid + i * 256;               // 2048 float4
            int row = f >> 5, c4 = (f & 31) << 2;
            float4 v = *(const float4*)(k_ws + (bh * LL + kv0 + row) * 128 + c4);
            ushort4 h, lo;
            cvt_hl(v.x, h.x, lo.x); cvt_hl(v.y, h.y, lo.y);
            cvt_hl(v.z, h.z, lo.z); cvt_hl(v.w, h.w, lo.w);
            *(ushort4*)&sh.kv.khi[row][c4] = h;
            *(ushort4*)&sh.kv.klo[row][c4] = lo;
        }
        for (int i = 0; i < 8; i++) {
            int f = tid + i * 256;
            int row = f >> 4, c4 = (f & 15) << 2;
            float4 v = *(const float4*)(v_ws + (bh * 128 + row) * LL + kv0 + c4);
            ushort4 h;
            h.x = f2bf(v.x); h.y = f2bf(v.y); h.z = f2bf(v.z); h.w = f2bf(v.w);
            *(ushort4*)&sh.kv.vv[row][c4] = h;
        }
        __syncthreads();

        // ---- S = Q K^T  (wave: 32 q rows x 64 kv cols) ----
        f32x4 s[2][4];
        for (int i = 0; i < 2; i++)
            for (int j = 0; j < 4; j++) s[i][j] = (f32x4)0.0f;
        for (int ks = 0; ks < 4; ks++) {
            bf16x8 k_hi[4], k_lo[4];
            for (int nt = 0; nt < 4; nt++) {
                int rr = nt * 16 + l16;
                k_hi[nt] = *(const bf16x8*)&sh.kv.khi[rr][ks * 32 + quad * 8];
                k_lo[nt] = *(const bf16x8*)&sh.kv.klo[rr][ks * 32 + quad * 8];
            }
            for (int mt = 0; mt < 2; mt++)
                for (int nt = 0; nt < 4; nt++) {
                    s[mt][nt] = __builtin_amdgcn_mfma_f32_16x16x32_bf16(q_hi[mt][ks], k_hi[nt], s[mt][nt], 0, 0, 0);
                    s[mt][nt] = __builtin_amdgcn_mfma_f32_16x16x32_bf16(q_hi[mt][ks], k_lo[nt], s[mt][nt], 0, 0, 0);
                    s[mt][nt] = __builtin_amdgcn_mfma_f32_16x16x32_bf16(q_lo[mt][ks], k_hi[nt], s[mt][nt], 0, 0, 0);
                }
        }
        __syncthreads();   // all waves done reading K -> khi region reusable for P

        // ---- online softmax ----
        unsigned short (*P)[72] = (unsigned short (*)[72])sh.kv.khi;
        for (int mt = 0; mt < 2; mt++) {
            for (int r = 0; r < 4; r++) {
                float mx = -INFINITY;
                for (int nt = 0; nt < 4; nt++) {
                    float v = s[mt][nt][r] * scale;
                    s[mt][nt][r] = v;
                    mx = fmaxf(mx, v);
                }
                for (int off = 1; off < 16; off <<= 1)
                    mx = fmaxf(mx, __shfl_xor(mx, off, 64));
                float mnew = fmaxf(m_st[mt][r], mx);
                float alpha = __expf(m_st[mt][r] - mnew);
                m_st[mt][r] = mnew;
                float sum = 0.0f;
                for (int nt = 0; nt < 4; nt++) {
                    float e = __expf(s[mt][nt][r] - mnew);
                    s[mt][nt][r] = e;
                    sum += e;
                }
                for (int off = 1; off < 16; off <<= 1)
                    sum += __shfl_xor(sum, off, 64);
                l_st[mt][r] = l_st[mt][r] * alpha + sum;
                for (int nto = 0; nto < 8; nto++) oacc[mt][nto][r] *= alpha;
            }
        }
        // write P (C layout) to LDS
        for (int mt = 0; mt < 2; mt++)
            for (int nt = 0; nt < 4; nt++)
                for (int r = 0; r < 4; r++) {
                    int row = wave * 32 + mt * 16 + quad * 4 + r;
                    int col = nt * 16 + l16;
                    P[row][col] = f2bf(s[mt][nt][r]);
                }
        __syncthreads();

        // ---- O += P @ V ----
        for (int ks = 0; ks < 2; ks++) {
            bf16x8 a[2];
            for (int mt = 0; mt < 2; mt++)
                a[mt] = *(const bf16x8*)&P[wave * 32 + mt * 16 + l16][ks * 32 + quad * 8];
            for (int nto = 0; nto < 8; nto++) {
                bf16x8 bfr = *(const bf16x8*)&sh.kv.vv[nto * 16 + l16][ks * 32 + quad * 8];
                for (int mt = 0; mt < 2; mt++)
                    oacc[mt][nto] = __builtin_amdgcn_mfma_f32_16x16x32_bf16(a[mt], bfr, oacc[mt][nto], 0, 0, 0);
            }
        }
        __syncthreads();   // before restaging K/V next iter
    }

    // ---- epilogue: O /= l, write to o_r / o_i [B*L][E] ----
    const int b = bh >> 4, h = bh & 15;
    for (int mt = 0; mt < 2; mt++)
        for (int r = 0; r < 4; r++) {
            float inv = 1.0f / l_st[mt][r];
            int lrow = q0 + wave * 32 + mt * 16 + quad * 4 + r;
            int rowbase = (b * LL + lrow) * EE + h * 64;
            for (int nto = 0; nto < 8; nto++) {
                int c = nto * 16 + l16;
                float v = oacc[mt][nto][r] * inv;
                if (nto < 4) o_r[rowbase + c] = v;
                else         o_i[rowbase + c - 64] = v;
            }
        }
}

// ---------------------------------------------------------------------------
extern "C" void kernel_launch(void* const* d_in, const int* in_sizes, int n_in,
                              void* d_out, int out_size, void* d_ws, size_t ws_size,
                              hipStream_t stream) {
    const float* query_r = (const float*)d_in[0];
    const float* query_i = (const float*)d_in[1];
    const float* key_r   = (const float*)d_in[2];
    const float* key_i   = (const float*)d_in[3];
    const float* value_r = (const float*)d_in[4];
    const float* value_i = (const float*)d_in[5];
    const float* Wq_r = (const float*)d_in[6];
    const float* Wq_i = (const float*)d_in[7];
    const float* bq_r = (const float*)d_in[8];
    const float* bq_i = (const float*)d_in[9];
    const float* Wk_r = (const float*)d_in[10];
    const float* Wk_i = (const float*)d_in[11];
    const float* bk_r = (const float*)d_in[12];
    const float* bk_i = (const float*)d_in[13];
    const float* Wv_r = (const float*)d_in[14];
    const float* Wv_i = (const float*)d_in[15];
    const float* bv_r = (const float*)d_in[16];
    const float* bv_i = (const float*)d_in[17];
    const float* Wo_r = (const float*)d_in[18];
    const float* Wo_i = (const float*)d_in[19];
    const float* bo_r = (const float*)d_in[20];
    const float* bo_i = (const float*)d_in[21];

    // workspace carve (fp32): q,k,v head-split + attention output (re/im)
    float* q_ws = (float*)d_ws;            // [32][2048][128] = 8,388,608
    float* k_ws = q_ws + 8388608;
    float* v_ws = k_ws + 8388608;          // [32][128][2048]
    float* o_r  = v_ws + 8388608;          // [4096][1024]
    float* o_i  = o_r  + 4194304;          // total 134,217,728 bytes

    dim3 blk(256);
    dim3 gproj(16, 32);   // n-tiles x m-tiles
    gemm_cplx<0><<<gproj, blk, 0, stream>>>(query_r, query_i, Wq_r, Wq_i, bq_r, bq_i, q_ws);
    gemm_cplx<0><<<gproj, blk, 0, stream>>>(key_r,   key_i,   Wk_r, Wk_i, bk_r, bk_i, k_ws);
    gemm_cplx<1><<<gproj, blk, 0, stream>>>(value_r, value_i, Wv_r, Wv_i, bv_r, bv_i, v_ws);
    attn<<<dim3(16, 32), blk, 0, stream>>>(q_ws, k_ws, v_ws, o_r, o_i);
    gemm_cplx<2><<<gproj, blk, 0, stream>>>(o_r, o_i, Wo_r, Wo_i, bo_r, bo_i, (float*)d_out);
}

// Round 2
// 497.893 us; speedup vs baseline: 2.2464x; 2.2464x over previous
//
#include <hip/hip_runtime.h>

// ComplexMultiheadAttention on MI355X (gfx950)  B=2, L=2048, E=1024, H=16, D=64
// R2: plain-bf16 everywhere (error budget allows), pre-convert passes,
// m97-style global_load_lds GEMMs with XOR-swizzled LDS, transposed-S flash
// attention with log2-domain softmax and covered async K/V staging.

#define LL 2048
#define EE 1024
#define HH 16
#define BL 4096   // B*L
#define KK 2048   // GEMM K (re||im)

typedef __attribute__((ext_vector_type(8))) short bf16x8;
typedef __attribute__((ext_vector_type(4))) float f32x4;
typedef unsigned short u16;

__device__ __forceinline__ u16 f2bf(float x) {
    unsigned u = __builtin_bit_cast(unsigned, x);
    u += 0x7fff + ((u >> 16) & 1);          // RNE
    return (u16)(u >> 16);
}

__device__ __forceinline__ void gl2lds16(const void* g, void* l) {
    __builtin_amdgcn_global_load_lds((const __attribute__((address_space(1))) void*)g,
                                     (__attribute__((address_space(3))) void*)l, 16, 0, 0);
}

// ---------------------------------------------------------------------------
// fp32 -> bf16 elementwise (vectorized), n4 = count of float4 groups
// ---------------------------------------------------------------------------
__global__ void conv_bf16(const float* __restrict__ in, u16* __restrict__ out, int n4) {
    int i = blockIdx.x * 256 + threadIdx.x;
    if (i >= n4) return;
    float4 v = ((const float4*)in)[i];
    ushort4 o;
    o.x = f2bf(v.x); o.y = f2bf(v.y); o.z = f2bf(v.z); o.w = f2bf(v.w);
    ((ushort4*)out)[i] = o;
}

// ---------------------------------------------------------------------------
// Build W2 bf16 [2048 n][2048 k]: n<1024: [Wr | -Wi] ; n>=1024: [Wi | Wr]
// ---------------------------------------------------------------------------
__global__ void conv_w2(const float* __restrict__ Wr, const float* __restrict__ Wi,
                        u16* __restrict__ W2) {
    int i = blockIdx.x * 256 + threadIdx.x;   // over 2048 * 512 float4-groups
    int n = i >> 9, k4 = i & 511;
    int k = k4 << 2;
    bool nh = n >= EE, kh = k >= EE;
    int nn = n & (EE - 1), kk = k & (EE - 1);
    const float* src = nh ? (kh ? Wr : Wi) : (kh ? Wi : Wr);
    float sgn = (!nh && kh) ? -1.0f : 1.0f;
    float4 v = *(const float4*)(src + nn * EE + kk);
    ushort4 o;
    o.x = f2bf(v.x * sgn); o.y = f2bf(v.y * sgn);
    o.z = f2bf(v.z * sgn); o.w = f2bf(v.w * sgn);
    *(ushort4*)(W2 + n * KK + k) = o;
}

// ---------------------------------------------------------------------------
// C[4096][2048] = [Ar|Ai] @ B2^T + bias   (all bf16 in, fp32 acc)
// m97 structure: 128x128 tile, BK=32, global_load_lds w=16, XOR-swizzled LDS.
// MODE 0: -> ws[bh][l][128] bf16 (Q/K head-split; oscale folds softmax scale)
// MODE 1: -> ws[bh][128][2048] bf16 (V transposed, feature-major)
// MODE 2: -> d_out fp32 [2][4096][1024]
// ---------------------------------------------------------------------------
template <int MODE>
__launch_bounds__(256, 2)
__global__ void gemm_bt(const u16* __restrict__ Ar, const u16* __restrict__ Ai,
                        const u16* __restrict__ B2,
                        const float* __restrict__ br, const float* __restrict__ bi,
                        void* __restrict__ outv, float oscale)
{
    __shared__ __attribute__((aligned(16))) u16 As[128 * 32];
    __shared__ __attribute__((aligned(16))) u16 Bs[128 * 32];

    const int tid = threadIdx.x, wave = tid >> 6, lane = tid & 63;
    const int quad = lane >> 4, l16 = lane & 15;
    const int m0 = blockIdx.y * 128, n0 = blockIdx.x * 128;
    const int wm = (wave >> 1) * 64, wn = (wave & 1) * 64;
    const int srow = lane >> 2, scl = lane & 3;   // staging lane coords

    f32x4 acc[4][4] = {};

    for (int k0 = 0; k0 < KK; k0 += 32) {
        const u16* Asrc = (k0 < EE) ? (Ar + k0) : (Ai + (k0 - EE));
        const u16* Bsrc = B2 + k0;
        __syncthreads();                       // prev step's frag reads done
        for (int t = 0; t < 2; t++) {
            int r0 = (wave * 2 + t) * 16 + srow;
            int cg = scl ^ ((r0 >> 1) & 3);
            gl2lds16(Asrc + (m0 + r0) * EE + cg * 8, &As[(wave * 2 + t) * 512]);
            gl2lds16(Bsrc + (n0 + r0) * KK + cg * 8, &Bs[(wave * 2 + t) * 512]);
        }
        __syncthreads();                       // DMA landed
        bf16x8 a[4], b[4];
        for (int t = 0; t < 4; t++) {
            int ra = wm + t * 16 + l16;
            a[t] = *(const bf16x8*)&As[ra * 32 + ((quad ^ ((ra >> 1) & 3)) << 3)];
            int rb = wn + t * 16 + l16;
            b[t] = *(const bf16x8*)&Bs[rb * 32 + ((quad ^ ((rb >> 1) & 3)) << 3)];
        }
        for (int i = 0; i < 4; i++)
            for (int j = 0; j < 4; j++)
                acc[i][j] = __builtin_amdgcn_mfma_f32_16x16x32_bf16(a[i], b[j], acc[i][j], 0, 0, 0);
    }

    // epilogue: C row = quad*4+reg, col = l16  [m89/m91]
    for (int j = 0; j < 4; j++) {
        int gn = n0 + wn + j * 16 + l16;
        int ri = gn >> 10, e = gn & 1023;
        float bias = ri ? bi[e] : br[e];
        for (int i = 0; i < 4; i++) {
            int gmb = m0 + wm + i * 16 + quad * 4;
            for (int r = 0; r < 4; r++) {
                int gm = gmb + r;
                float v = (acc[i][j][r] + bias) * oscale;
                if (MODE == 2) {
                    ((float*)outv)[ri * (BL * EE) + gm * EE + e] = v;
                } else {
                    int b = gm >> 11, l = gm & 2047;
                    int h = e >> 6, d = e & 63;
                    u16* o = (u16*)outv;
                    if (MODE == 0)
                        o[((b * HH + h) * LL + l) * 128 + ri * 64 + d] = f2bf(v);
                    else
                        o[((b * HH + h) * 128 + ri * 64 + d) * LL + l] = f2bf(v);
                }
            }
        }
    }
}

// ---------------------------------------------------------------------------
// Flash attention, transposed-S formulation.
// q_ws/k_ws: bf16 [bh][l][128]  (Q pre-scaled by 0.125*log2e)
// v_ws:      bf16 [bh][128][2048]
// Block: 128 q rows, 4 waves x 32 q (ntq=2). BKV=64/iter.
// S^T = K·Q^T (Q frags = B operand, in regs). Softmax in log2 domain.
// P overwrites the just-consumed K buffer; K double-buffered, V single;
// async global_load_lds issued after barrier B, drained at next barrier A
// (covered by a full QK+softmax phase).
// ---------------------------------------------------------------------------
__launch_bounds__(256, 2)
__global__ void attn(const u16* __restrict__ q_ws, const u16* __restrict__ k_ws,
                     const u16* __restrict__ v_ws,
                     u16* __restrict__ o_r, u16* __restrict__ o_i)
{
    __shared__ __attribute__((aligned(16))) u16 kbuf[2][64 * 128];  // 2x16 KB
    __shared__ __attribute__((aligned(16))) u16 vbuf[128 * 64];     // 16 KB
    __shared__ __attribute__((aligned(16))) float red_sh[4][32];

    const int tid = threadIdx.x, wave = tid >> 6, lane = tid & 63;
    const int quad = lane >> 4, l16 = lane & 15;
    const int q0 = blockIdx.x * 128, bh = blockIdx.y;

    // Q fragments (B-operand layout == A layout: row = l16, k = quad*8+j)
    bf16x8 qf[2][4];
    for (int ntq = 0; ntq < 2; ntq++) {
        const u16* qp = q_ws + (size_t)(bh * LL + q0 + wave * 32 + ntq * 16 + l16) * 128 + quad * 8;
        for (int ks = 0; ks < 4; ks++)
            qf[ntq][ks] = *(const bf16x8*)(qp + ks * 32);
    }

    // staging: K tile [64 kv][128 d] (16 chunks/row), V tile [128 d][64 kv] (8 chunks/row)
    auto stage_k = [&](int nb, int kv0) {
        for (int t = 0; t < 4; t++) {
            int s = wave * 4 + t;
            int row = s * 4 + (lane >> 4);
            int cg = (lane & 15) ^ (row & 15);
            gl2lds16(k_ws + (size_t)(bh * LL + kv0 + row) * 128 + cg * 8, &kbuf[nb][s * 512]);
        }
    };
    auto stage_v = [&](int kv0) {
        for (int t = 0; t < 4; t++) {
            int s = wave * 4 + t;
            int row = s * 8 + (lane >> 3);
            int cg = (lane & 7) ^ (row & 7);
            gl2lds16(v_ws + (size_t)(bh * 128 + row) * LL + kv0 + cg * 8, &vbuf[s * 512]);
        }
    };

    stage_k(0, 0);
    stage_v(0);
    stage_k(1, 64);
    __syncthreads();

    f32x4 oacc[2][8] = {};
    float m_st[2] = {-__builtin_inff(), -__builtin_inff()};
    float l_st[2] = {0.f, 0.f};

    for (int N = 0; N < 32; N++) {
        const int cur = N & 1;
        u16* K = kbuf[cur];

        // ---- S^T[64 kv][32 q] = K · Q^T ----
        f32x4 s[4][2] = {};
        for (int ks = 0; ks < 4; ks++) {
            bf16x8 kf[4];
            for (int mt = 0; mt < 4; mt++) {
                int row = mt * 16 + l16;
                int cl = (ks * 4 + quad) ^ (row & 15);
                kf[mt] = *(const bf16x8*)&K[row * 128 + cl * 8];
            }
            for (int mt = 0; mt < 4; mt++)
                for (int ntq = 0; ntq < 2; ntq++)
                    s[mt][ntq] = __builtin_amdgcn_mfma_f32_16x16x32_bf16(kf[mt], qf[ntq][ks], s[mt][ntq], 0, 0, 0);
        }

        // ---- online softmax (log2 domain); row q lives in 16 lanes x 4 quads ----
        bool changed = false;
        float alpha[2];
        for (int ntq = 0; ntq < 2; ntq++) {
            float mx = -__builtin_inff();
            for (int mt = 0; mt < 4; mt++)
                for (int r = 0; r < 4; r++)
                    mx = fmaxf(mx, s[mt][ntq][r]);
            mx = fmaxf(mx, __shfl_xor(mx, 16, 64));
            mx = fmaxf(mx, __shfl_xor(mx, 32, 64));
            float mnew = fmaxf(m_st[ntq], mx);
            changed |= (mnew != m_st[ntq]);
            alpha[ntq] = __builtin_amdgcn_exp2f(m_st[ntq] - mnew);
            m_st[ntq] = mnew;
            float sum = 0.f;
            for (int mt = 0; mt < 4; mt++)
                for (int r = 0; r < 4; r++) {
                    float p = __builtin_amdgcn_exp2f(s[mt][ntq][r] - mnew);
                    s[mt][ntq][r] = p;
                    sum += p;
                }
            sum += __shfl_xor(sum, 16, 64);
            sum += __shfl_xor(sum, 32, 64);
            l_st[ntq] = l_st[ntq] * alpha[ntq] + sum;
            if (quad == 0) red_sh[wave][ntq * 16 + l16] = alpha[ntq];
        }
        __syncthreads();   // barrier A: K[cur] reads done; drains prev async loads

        // ---- P (A-layout [32 q][64 kv]) into own quarter of kbuf[cur] ----
        u16* P = kbuf[cur] + wave * 2048;
        for (int ntq = 0; ntq < 2; ntq++)
            for (int mt = 0; mt < 4; mt++) {
                int q = ntq * 16 + l16;
                int cg = mt * 2 + (quad >> 1);
                int cl = cg ^ (q & 7);
                ushort4 pk;
                pk.x = f2bf(s[mt][ntq][0]); pk.y = f2bf(s[mt][ntq][1]);
                pk.z = f2bf(s[mt][ntq][2]); pk.w = f2bf(s[mt][ntq][3]);
                *(ushort4*)&P[q * 64 + cl * 8 + (quad & 1) * 4] = pk;
            }

        // ---- O rescale (skip when running max unchanged wave-wide) ----
        if (__any(changed)) {
            f32x4 av[2];
            av[0] = *(const f32x4*)&red_sh[wave][quad * 4];
            av[1] = *(const f32x4*)&red_sh[wave][16 + quad * 4];
            for (int mtq = 0; mtq < 2; mtq++)
                for (int nt = 0; nt < 8; nt++)
                    oacc[mtq][nt] *= av[mtq];
        }

        // ---- O += P @ V ----
        for (int ks = 0; ks < 2; ks++) {
            bf16x8 pf[2];
            for (int mtq = 0; mtq < 2; mtq++) {
                int q = mtq * 16 + l16;
                int cl = (ks * 4 + quad) ^ (q & 7);
                pf[mtq] = *(const bf16x8*)&P[q * 64 + cl * 8];
            }
            for (int nt = 0; nt < 8; nt++) {
                int row = nt * 16 + l16;
                int cl = (ks * 4 + quad) ^ (row & 7);
                bf16x8 vf = *(const bf16x8*)&vbuf[row * 64 + cl * 8];
                for (int mtq = 0; mtq < 2; mtq++)
                    oacc[mtq][nt] = __builtin_amdgcn_mfma_f32_16x16x32_bf16(pf[mtq], vf, oacc[mtq][nt], 0, 0, 0);
            }
        }
        __syncthreads();   // barrier B: PV done everywhere; P dead, vbuf free

        if (N + 2 < 32) stage_k(cur, (N + 2) * 64);   // into region P occupied
        if (N + 1 < 32) stage_v((N + 1) * 64);
    }

    // ---- epilogue: O /= l, write bf16 o_r/o_i [4096][1024] ----
    if (quad == 0) {
        red_sh[wave][l16] = l_st[0];
        red_sh[wave][16 + l16] = l_st[1];
    }
    __syncthreads();
    f32x4 lv[2];
    lv[0] = *(const f32x4*)&red_sh[wave][quad * 4];
    lv[1] = *(const f32x4*)&red_sh[wave][16 + quad * 4];
    const int b = bh >> 4, h = bh & 15;
    for (int mtq = 0; mtq < 2; mtq++) {
        f32x4 inv;
        for (int r = 0; r < 4; r++) inv[r] = 1.0f / lv[mtq][r];
        for (int nt = 0; nt < 8; nt++) {
            int d2 = nt * 16 + l16;
            u16* op = (d2 < 64) ? o_r : o_i;
            int col = h * 64 + (d2 & 63);
            for (int r = 0; r < 4; r++) {
                int l = q0 + wave * 32 + mtq * 16 + quad * 4 + r;
                op[(size_t)(b * LL + l) * EE + col] = f2bf(oacc[mtq][nt][r] * inv[r]);
            }
        }
    }
}

// ---------------------------------------------------------------------------
extern "C" void kernel_launch(void* const* d_in, const int* in_sizes, int n_in,
                              void* d_out, int out_size, void* d_ws, size_t ws_size,
                              hipStream_t stream) {
    const float* query_r = (const float*)d_in[0];
    const float* query_i = (const float*)d_in[1];
    const float* key_r   = (const float*)d_in[2];
    const float* key_i   = (const float*)d_in[3];
    const float* value_r = (const float*)d_in[4];
    const float* value_i = (const float*)d_in[5];
    const float* Wq_r = (const float*)d_in[6];
    const float* Wq_i = (const float*)d_in[7];
    const float* bq_r = (const float*)d_in[8];
    const float* bq_i = (const float*)d_in[9];
    const float* Wk_r = (const float*)d_in[10];
    const float* Wk_i = (const float*)d_in[11];
    const float* bk_r = (const float*)d_in[12];
    const float* bk_i = (const float*)d_in[13];
    const float* Wv_r = (const float*)d_in[14];
    const float* Wv_i = (const float*)d_in[15];
    const float* bv_r = (const float*)d_in[16];
    const float* bv_i = (const float*)d_in[17];
    const float* Wo_r = (const float*)d_in[18];
    const float* Wo_i = (const float*)d_in[19];
    const float* bo_r = (const float*)d_in[20];
    const float* bo_i = (const float*)d_in[21];

    u16* ws = (u16*)d_ws;
    const size_t XN = 4194304;          // 4096*1024 (also 2048*2048/... W2 = 4194304)
    u16* xqr = ws;            u16* xqi = xqr + XN;
    u16* xkr = xqi + XN;      u16* xki = xkr + XN;
    u16* xvr = xki + XN;      u16* xvi = xvr + XN;
    u16* w2q = xvi + XN;
    u16* w2k = w2q + XN;
    u16* w2v = w2k + XN;
    u16* w2o = w2v + XN;
    u16* q_ws = w2o + XN;               // 32*2048*128 = 8388608
    u16* k_ws = q_ws + 8388608;
    u16* v_ws = k_ws + 8388608;
    u16* o_r = xqr;                     // alias: X regions dead after QKV GEMMs
    u16* o_i = xqr + XN;
    // total: 10*XN + 3*8388608 = 134,217,728 bytes (same footprint as R1)

    dim3 blk(256);
    const int N4 = 1048576;             // 4096*1024/4
    conv_bf16<<<4096, blk, 0, stream>>>(query_r, xqr, N4);
    conv_bf16<<<4096, blk, 0, stream>>>(query_i, xqi, N4);
    conv_bf16<<<4096, blk, 0, stream>>>(key_r,   xkr, N4);
    conv_bf16<<<4096, blk, 0, stream>>>(key_i,   xki, N4);
    conv_bf16<<<4096, blk, 0, stream>>>(value_r, xvr, N4);
    conv_bf16<<<4096, blk, 0, stream>>>(value_i, xvi, N4);
    conv_w2<<<4096, blk, 0, stream>>>(Wq_r, Wq_i, w2q);
    conv_w2<<<4096, blk, 0, stream>>>(Wk_r, Wk_i, w2k);
    conv_w2<<<4096, blk, 0, stream>>>(Wv_r, Wv_i, w2v);
    conv_w2<<<4096, blk, 0, stream>>>(Wo_r, Wo_i, w2o);

    const float QSCALE = 0.125f * 1.44269504088896f;   // 1/sqrt(D) * log2(e)
    dim3 gproj(16, 32);
    gemm_bt<0><<<gproj, blk, 0, stream>>>(xqr, xqi, w2q, bq_r, bq_i, q_ws, QSCALE);
    gemm_bt<0><<<gproj, blk, 0, stream>>>(xkr, xki, w2k, bk_r, bk_i, k_ws, 1.0f);
    gemm_bt<1><<<gproj, blk, 0, stream>>>(xvr, xvi, w2v, bv_r, bv_i, v_ws, 1.0f);
    attn<<<dim3(16, 32), blk, 0, stream>>>(q_ws, k_ws, v_ws, o_r, o_i);
    gemm_bt<2><<<gproj, blk, 0, stream>>>(o_r, o_i, w2o, bo_r, bo_i, (float*)d_out, 1.0f);
}

// Round 5
// 479.850 us; speedup vs baseline: 2.3308x; 1.0376x over previous
//
#include <hip/hip_runtime.h>

// ComplexMultiheadAttention on MI355X (gfx950)  B=2, L=2048, E=1024, H=16, D=64
// R5 BISECTION: R3/R4 failed with identical absmax despite on-paper-correct
// math. This round keeps the R3 launch merges (conv 10->2, QKV GEMMs 3->1)
// but reverts attn to the BYTE-IDENTICAL R2 online-softmax kernel (known
// good, absmax 0.039). Pass => fixed-shift softmax was the bug (drop it).
// Fail => merges are the bug (revert them next).

#define LL 2048
#define EE 1024
#define HH 16
#define BL 4096   // B*L
#define KK 2048   // GEMM K (re||im)

typedef __attribute__((ext_vector_type(8))) short bf16x8;
typedef __attribute__((ext_vector_type(4))) float f32x4;
typedef unsigned short u16;

__device__ __forceinline__ u16 f2bf(float x) {
    unsigned u = __builtin_bit_cast(unsigned, x);
    u += 0x7fff + ((u >> 16) & 1);          // RNE
    return (u16)(u >> 16);
}

__device__ __forceinline__ void gl2lds16(const void* g, void* l) {
    __builtin_amdgcn_global_load_lds((const __attribute__((address_space(1))) void*)g,
                                     (__attribute__((address_space(3))) void*)l, 16, 0, 0);
}

// ---------------------------------------------------------------------------
// Merged fp32->bf16 conversion: 6 activation tensors, grid (4096, 6)
// ---------------------------------------------------------------------------
struct ConvXArgs { const float* src[6]; u16* dst[6]; };
__global__ void conv_x(ConvXArgs a) {
    const int z = blockIdx.y;
    int i = blockIdx.x * 256 + threadIdx.x;     // 1,048,576 float4 groups exactly
    float4 v = ((const float4*)a.src[z])[i];
    ushort4 o;
    o.x = f2bf(v.x); o.y = f2bf(v.y); o.z = f2bf(v.z); o.w = f2bf(v.w);
    ((ushort4*)a.dst[z])[i] = o;
}

// ---------------------------------------------------------------------------
// Merged W2 build: 4 weight pairs, grid (4096, 4)
// W2 bf16 [2048 n][2048 k]: n<1024: [Wr | -Wi] ; n>=1024: [Wi | Wr]
// ---------------------------------------------------------------------------
struct ConvWArgs { const float* wr[4]; const float* wi[4]; u16* w2[4]; };
__global__ void conv_w(ConvWArgs a) {
    const int z = blockIdx.y;
    int i = blockIdx.x * 256 + threadIdx.x;     // 2048*512 groups exactly
    int n = i >> 9, k = (i & 511) << 2;
    bool nh = n >= EE, kh = k >= EE;
    int nn = n & (EE - 1), kk = k & (EE - 1);
    const float* src = nh ? (kh ? a.wr[z] : a.wi[z]) : (kh ? a.wi[z] : a.wr[z]);
    float sgn = (!nh && kh) ? -1.0f : 1.0f;
    float4 v = *(const float4*)(src + nn * EE + kk);
    ushort4 o;
    o.x = f2bf(v.x * sgn); o.y = f2bf(v.y * sgn);
    o.z = f2bf(v.z * sgn); o.w = f2bf(v.w * sgn);
    *(ushort4*)(a.w2[z] + n * KK + k) = o;
}

// ---------------------------------------------------------------------------
// Merged Q/K/V projection GEMM: grid (16, 32, 3), z selects tensor.
// C[4096][2048] = [Ar|Ai] @ B2^T + bias; 128x128 tile, BK=32,
// global_load_lds w=16, XOR-swizzled LDS.
// z=0 (Q) / z=1 (K): epilogue -> ws[bh][l][128] bf16 (Q scaled by oscale)
// z=2 (V):           epilogue -> ws[bh][128][2048] bf16 (transposed)
// ---------------------------------------------------------------------------
struct QKVArgs {
    const u16* Ar[3]; const u16* Ai[3]; const u16* B2[3];
    const float* br[3]; const float* bi[3];
    u16* out[3];
    float oscale[3];
};

__launch_bounds__(256, 3)
__global__ void gemm_qkv(QKVArgs args) {
    __shared__ __attribute__((aligned(16))) u16 As[128 * 32];
    __shared__ __attribute__((aligned(16))) u16 Bs[128 * 32];

    const int z = blockIdx.z;
    const u16* __restrict__ Ar = args.Ar[z];
    const u16* __restrict__ Ai = args.Ai[z];
    const u16* __restrict__ B2 = args.B2[z];

    const int tid = threadIdx.x, wave = tid >> 6, lane = tid & 63;
    const int quad = lane >> 4, l16 = lane & 15;
    const int m0 = blockIdx.y * 128, n0 = blockIdx.x * 128;
    const int wm = (wave >> 1) * 64, wn = (wave & 1) * 64;
    const int srow = lane >> 2, scl = lane & 3;

    f32x4 acc[4][4] = {};

    for (int k0 = 0; k0 < KK; k0 += 32) {
        const u16* Asrc = (k0 < EE) ? (Ar + k0) : (Ai + (k0 - EE));
        const u16* Bsrc = B2 + k0;
        __syncthreads();
        for (int t = 0; t < 2; t++) {
            int r0 = (wave * 2 + t) * 16 + srow;
            int cg = scl ^ ((r0 >> 1) & 3);
            gl2lds16(Asrc + (m0 + r0) * EE + cg * 8, &As[(wave * 2 + t) * 512]);
            gl2lds16(Bsrc + (n0 + r0) * KK + cg * 8, &Bs[(wave * 2 + t) * 512]);
        }
        __syncthreads();
        bf16x8 a[4], b[4];
        for (int t = 0; t < 4; t++) {
            int ra = wm + t * 16 + l16;
            a[t] = *(const bf16x8*)&As[ra * 32 + ((quad ^ ((ra >> 1) & 3)) << 3)];
            int rb = wn + t * 16 + l16;
            b[t] = *(const bf16x8*)&Bs[rb * 32 + ((quad ^ ((rb >> 1) & 3)) << 3)];
        }
        for (int i = 0; i < 4; i++)
            for (int j = 0; j < 4; j++)
                acc[i][j] = __builtin_amdgcn_mfma_f32_16x16x32_bf16(a[i], b[j], acc[i][j], 0, 0, 0);
    }

    const float* __restrict__ br_ = args.br[z];
    const float* __restrict__ bi_ = args.bi[z];
    u16* __restrict__ out = args.out[z];
    const float oscale = args.oscale[z];

    for (int j = 0; j < 4; j++) {
        int gn = n0 + wn + j * 16 + l16;
        int ri = gn >> 10, e = gn & 1023;
        float bias = ri ? bi_[e] : br_[e];
        for (int i = 0; i < 4; i++) {
            int gmb = m0 + wm + i * 16 + quad * 4;
            for (int r = 0; r < 4; r++) {
                int gm = gmb + r;
                float v = (acc[i][j][r] + bias) * oscale;
                int b = gm >> 11, l = gm & 2047;
                int h = e >> 6, d = e & 63;
                if (z < 2)
                    out[((b * HH + h) * LL + l) * 128 + ri * 64 + d] = f2bf(v);
                else
                    out[((b * HH + h) * 128 + ri * 64 + d) * LL + l] = f2bf(v);
            }
        }
    }
}

// ---------------------------------------------------------------------------
// Output projection GEMM -> d_out fp32 [2][4096][1024]
// ---------------------------------------------------------------------------
__launch_bounds__(256, 2)
__global__ void gemm_oproj(const u16* __restrict__ Ar, const u16* __restrict__ Ai,
                           const u16* __restrict__ B2,
                           const float* __restrict__ br, const float* __restrict__ bi,
                           float* __restrict__ out)
{
    __shared__ __attribute__((aligned(16))) u16 As[128 * 32];
    __shared__ __attribute__((aligned(16))) u16 Bs[128 * 32];

    const int tid = threadIdx.x, wave = tid >> 6, lane = tid & 63;
    const int quad = lane >> 4, l16 = lane & 15;
    const int m0 = blockIdx.y * 128, n0 = blockIdx.x * 128;
    const int wm = (wave >> 1) * 64, wn = (wave & 1) * 64;
    const int srow = lane >> 2, scl = lane & 3;

    f32x4 acc[4][4] = {};

    for (int k0 = 0; k0 < KK; k0 += 32) {
        const u16* Asrc = (k0 < EE) ? (Ar + k0) : (Ai + (k0 - EE));
        const u16* Bsrc = B2 + k0;
        __syncthreads();
        for (int t = 0; t < 2; t++) {
            int r0 = (wave * 2 + t) * 16 + srow;
            int cg = scl ^ ((r0 >> 1) & 3);
            gl2lds16(Asrc + (m0 + r0) * EE + cg * 8, &As[(wave * 2 + t) * 512]);
            gl2lds16(Bsrc + (n0 + r0) * KK + cg * 8, &Bs[(wave * 2 + t) * 512]);
        }
        __syncthreads();
        bf16x8 a[4], b[4];
        for (int t = 0; t < 4; t++) {
            int ra = wm + t * 16 + l16;
            a[t] = *(const bf16x8*)&As[ra * 32 + ((quad ^ ((ra >> 1) & 3)) << 3)];
            int rb = wn + t * 16 + l16;
            b[t] = *(const bf16x8*)&Bs[rb * 32 + ((quad ^ ((rb >> 1) & 3)) << 3)];
        }
        for (int i = 0; i < 4; i++)
            for (int j = 0; j < 4; j++)
                acc[i][j] = __builtin_amdgcn_mfma_f32_16x16x32_bf16(a[i], b[j], acc[i][j], 0, 0, 0);
    }

    for (int j = 0; j < 4; j++) {
        int gn = n0 + wn + j * 16 + l16;
        int ri = gn >> 10, e = gn & 1023;
        float bias = ri ? bi[e] : br[e];
        for (int i = 0; i < 4; i++) {
            int gmb = m0 + wm + i * 16 + quad * 4;
            for (int r = 0; r < 4; r++) {
                int gm = gmb + r;
                out[ri * (BL * EE) + gm * EE + e] = acc[i][j][r] + bias;
            }
        }
    }
}

// ---------------------------------------------------------------------------
// Flash attention — VERBATIM R2 kernel (known good): transposed-S, online
// softmax in log2 domain, P through LDS, async K/V staging.
// q_ws/k_ws: bf16 [bh][l][128] (Q pre-scaled by 0.125*log2e); v_ws: [bh][128][2048]
// ---------------------------------------------------------------------------
__launch_bounds__(256, 2)
__global__ void attn(const u16* __restrict__ q_ws, const u16* __restrict__ k_ws,
                     const u16* __restrict__ v_ws,
                     u16* __restrict__ o_r, u16* __restrict__ o_i)
{
    __shared__ __attribute__((aligned(16))) u16 kbuf[2][64 * 128];  // 2x16 KB
    __shared__ __attribute__((aligned(16))) u16 vbuf[128 * 64];     // 16 KB
    __shared__ __attribute__((aligned(16))) float red_sh[4][32];

    const int tid = threadIdx.x, wave = tid >> 6, lane = tid & 63;
    const int quad = lane >> 4, l16 = lane & 15;
    const int q0 = blockIdx.x * 128, bh = blockIdx.y;

    // Q fragments (B-operand layout: row = l16, k = quad*8+j)
    bf16x8 qf[2][4];
    for (int ntq = 0; ntq < 2; ntq++) {
        const u16* qp = q_ws + (size_t)(bh * LL + q0 + wave * 32 + ntq * 16 + l16) * 128 + quad * 8;
        for (int ks = 0; ks < 4; ks++)
            qf[ntq][ks] = *(const bf16x8*)(qp + ks * 32);
    }

    auto stage_k = [&](int nb, int kv0) {
        for (int t = 0; t < 4; t++) {
            int s = wave * 4 + t;
            int row = s * 4 + (lane >> 4);
            int cg = (lane & 15) ^ (row & 15);
            gl2lds16(k_ws + (size_t)(bh * LL + kv0 + row) * 128 + cg * 8, &kbuf[nb][s * 512]);
        }
    };
    auto stage_v = [&](int kv0) {
        for (int t = 0; t < 4; t++) {
            int s = wave * 4 + t;
            int row = s * 8 + (lane >> 3);
            int cg = (lane & 7) ^ (row & 7);
            gl2lds16(v_ws + (size_t)(bh * 128 + row) * LL + kv0 + cg * 8, &vbuf[s * 512]);
        }
    };

    stage_k(0, 0);
    stage_v(0);
    stage_k(1, 64);
    __syncthreads();

    f32x4 oacc[2][8] = {};
    float m_st[2] = {-__builtin_inff(), -__builtin_inff()};
    float l_st[2] = {0.f, 0.f};

    for (int N = 0; N < 32; N++) {
        const int cur = N & 1;
        u16* K = kbuf[cur];

        // ---- S^T[64 kv][32 q] = K . Q^T ----
        f32x4 s[4][2] = {};
        for (int ks = 0; ks < 4; ks++) {
            bf16x8 kf[4];
            for (int mt = 0; mt < 4; mt++) {
                int row = mt * 16 + l16;
                int cl = (ks * 4 + quad) ^ (row & 15);
                kf[mt] = *(const bf16x8*)&K[row * 128 + cl * 8];
            }
            for (int mt = 0; mt < 4; mt++)
                for (int ntq = 0; ntq < 2; ntq++)
                    s[mt][ntq] = __builtin_amdgcn_mfma_f32_16x16x32_bf16(kf[mt], qf[ntq][ks], s[mt][ntq], 0, 0, 0);
        }

        // ---- online softmax (log2 domain); row q lives in 16 lanes x 4 quads ----
        bool changed = false;
        float alpha[2];
        for (int ntq = 0; ntq < 2; ntq++) {
            float mx = -__builtin_inff();
            for (int mt = 0; mt < 4; mt++)
                for (int r = 0; r < 4; r++)
                    mx = fmaxf(mx, s[mt][ntq][r]);
            mx = fmaxf(mx, __shfl_xor(mx, 16, 64));
            mx = fmaxf(mx, __shfl_xor(mx, 32, 64));
            float mnew = fmaxf(m_st[ntq], mx);
            changed |= (mnew != m_st[ntq]);
            alpha[ntq] = __builtin_amdgcn_exp2f(m_st[ntq] - mnew);
            m_st[ntq] = mnew;
            float sum = 0.f;
            for (int mt = 0; mt < 4; mt++)
                for (int r = 0; r < 4; r++) {
                    float p = __builtin_amdgcn_exp2f(s[mt][ntq][r] - mnew);
                    s[mt][ntq][r] = p;
                    sum += p;
                }
            sum += __shfl_xor(sum, 16, 64);
            sum += __shfl_xor(sum, 32, 64);
            l_st[ntq] = l_st[ntq] * alpha[ntq] + sum;
            if (quad == 0) red_sh[wave][ntq * 16 + l16] = alpha[ntq];
        }
        __syncthreads();   // barrier A: K[cur] reads done; drains prev async loads

        // ---- P (A-layout [32 q][64 kv]) into own quarter of kbuf[cur] ----
        u16* P = kbuf[cur] + wave * 2048;
        for (int ntq = 0; ntq < 2; ntq++)
            for (int mt = 0; mt < 4; mt++) {
                int q = ntq * 16 + l16;
                int cg = mt * 2 + (quad >> 1);
                int cl = cg ^ (q & 7);
                ushort4 pk;
                pk.x = f2bf(s[mt][ntq][0]); pk.y = f2bf(s[mt][ntq][1]);
                pk.z = f2bf(s[mt][ntq][2]); pk.w = f2bf(s[mt][ntq][3]);
                *(ushort4*)&P[q * 64 + cl * 8 + (quad & 1) * 4] = pk;
            }

        // ---- O rescale (skip when running max unchanged wave-wide) ----
        if (__any(changed)) {
            f32x4 av[2];
            av[0] = *(const f32x4*)&red_sh[wave][quad * 4];
            av[1] = *(const f32x4*)&red_sh[wave][16 + quad * 4];
            for (int mtq = 0; mtq < 2; mtq++)
                for (int nt = 0; nt < 8; nt++)
                    oacc[mtq][nt] *= av[mtq];
        }

        // ---- O += P @ V ----
        for (int ks = 0; ks < 2; ks++) {
            bf16x8 pf[2];
            for (int mtq = 0; mtq < 2; mtq++) {
                int q = mtq * 16 + l16;
                int cl = (ks * 4 + quad) ^ (q & 7);
                pf[mtq] = *(const bf16x8*)&P[q * 64 + cl * 8];
            }
            for (int nt = 0; nt < 8; nt++) {
                int row = nt * 16 + l16;
                int cl = (ks * 4 + quad) ^ (row & 7);
                bf16x8 vf = *(const bf16x8*)&vbuf[row * 64 + cl * 8];
                for (int mtq = 0; mtq < 2; mtq++)
                    oacc[mtq][nt] = __builtin_amdgcn_mfma_f32_16x16x32_bf16(pf[mtq], vf, oacc[mtq][nt], 0, 0, 0);
            }
        }
        __syncthreads();   // barrier B: PV done everywhere; P dead, vbuf free

        if (N + 2 < 32) stage_k(cur, (N + 2) * 64);   // into region P occupied
        if (N + 1 < 32) stage_v((N + 1) * 64);
    }

    // ---- epilogue: O /= l, write bf16 o_r/o_i [4096][1024] ----
    if (quad == 0) {
        red_sh[wave][l16] = l_st[0];
        red_sh[wave][16 + l16] = l_st[1];
    }
    __syncthreads();
    f32x4 lv[2];
    lv[0] = *(const f32x4*)&red_sh[wave][quad * 4];
    lv[1] = *(const f32x4*)&red_sh[wave][16 + quad * 4];
    const int b = bh >> 4, h = bh & 15;
    for (int mtq = 0; mtq < 2; mtq++) {
        f32x4 inv;
        for (int r = 0; r < 4; r++) inv[r] = 1.0f / lv[mtq][r];
        for (int nt = 0; nt < 8; nt++) {
            int d2 = nt * 16 + l16;
            u16* op = (d2 < 64) ? o_r : o_i;
            int col = h * 64 + (d2 & 63);
            for (int r = 0; r < 4; r++) {
                int l = q0 + wave * 32 + mtq * 16 + quad * 4 + r;
                op[(size_t)(b * LL + l) * EE + col] = f2bf(oacc[mtq][nt][r] * inv[r]);
            }
        }
    }
}

// ---------------------------------------------------------------------------
extern "C" void kernel_launch(void* const* d_in, const int* in_sizes, int n_in,
                              void* d_out, int out_size, void* d_ws, size_t ws_size,
                              hipStream_t stream) {
    const float* bq_r = (const float*)d_in[8];
    const float* bq_i = (const float*)d_in[9];
    const float* bk_r = (const float*)d_in[12];
    const float* bk_i = (const float*)d_in[13];
    const float* bv_r = (const float*)d_in[16];
    const float* bv_i = (const float*)d_in[17];
    const float* bo_r = (const float*)d_in[20];
    const float* bo_i = (const float*)d_in[21];

    u16* ws = (u16*)d_ws;
    const size_t XN = 4194304;          // 4096*1024 elements (= 2048*2048)
    u16* xqr = ws;            u16* xqi = xqr + XN;
    u16* xkr = xqi + XN;      u16* xki = xkr + XN;
    u16* xvr = xki + XN;      u16* xvi = xvr + XN;
    u16* w2q = xvi + XN;
    u16* w2k = w2q + XN;
    u16* w2v = w2k + XN;
    u16* w2o = w2v + XN;
    u16* q_ws = w2o + XN;               // 32*2048*128 = 8,388,608
    u16* k_ws = q_ws + 8388608;
    u16* v_ws = k_ws + 8388608;
    u16* o_r = xqr;                     // X regions dead after QKV GEMMs
    u16* o_i = xqr + XN;

    dim3 blk(256);

    ConvXArgs cx;
    cx.src[0] = (const float*)d_in[0]; cx.dst[0] = xqr;
    cx.src[1] = (const float*)d_in[1]; cx.dst[1] = xqi;
    cx.src[2] = (const float*)d_in[2]; cx.dst[2] = xkr;
    cx.src[3] = (const float*)d_in[3]; cx.dst[3] = xki;
    cx.src[4] = (const float*)d_in[4]; cx.dst[4] = xvr;
    cx.src[5] = (const float*)d_in[5]; cx.dst[5] = xvi;
    conv_x<<<dim3(4096, 6), blk, 0, stream>>>(cx);

    ConvWArgs cw;
    cw.wr[0] = (const float*)d_in[6];  cw.wi[0] = (const float*)d_in[7];  cw.w2[0] = w2q;
    cw.wr[1] = (const float*)d_in[10]; cw.wi[1] = (const float*)d_in[11]; cw.w2[1] = w2k;
    cw.wr[2] = (const float*)d_in[14]; cw.wi[2] = (const float*)d_in[15]; cw.w2[2] = w2v;
    cw.wr[3] = (const float*)d_in[18]; cw.wi[3] = (const float*)d_in[19]; cw.w2[3] = w2o;
    conv_w<<<dim3(4096, 4), blk, 0, stream>>>(cw);

    const float QSCALE = 0.125f * 1.44269504088896f;   // 1/sqrt(D) * log2(e)
    QKVArgs qa;
    qa.Ar[0] = xqr; qa.Ai[0] = xqi; qa.B2[0] = w2q; qa.br[0] = bq_r; qa.bi[0] = bq_i; qa.out[0] = q_ws; qa.oscale[0] = QSCALE;
    qa.Ar[1] = xkr; qa.Ai[1] = xki; qa.B2[1] = w2k; qa.br[1] = bk_r; qa.bi[1] = bk_i; qa.out[1] = k_ws; qa.oscale[1] = 1.0f;
    qa.Ar[2] = xvr; qa.Ai[2] = xvi; qa.B2[2] = w2v; qa.br[2] = bv_r; qa.bi[2] = bv_i; qa.out[2] = v_ws; qa.oscale[2] = 1.0f;
    gemm_qkv<<<dim3(16, 32, 3), blk, 0, stream>>>(qa);

    attn<<<dim3(16, 32), blk, 0, stream>>>(q_ws, k_ws, v_ws, o_r, o_i);

    gemm_oproj<<<dim3(16, 32), blk, 0, stream>>>(o_r, o_i, w2o, bo_r, bo_i, (float*)d_out);
}

// Round 6
// 468.525 us; speedup vs baseline: 2.3872x; 1.0242x over previous
//
#include <hip/hip_runtime.h>

// ComplexMultiheadAttention on MI355X (gfx950)  B=2, L=2048, E=1024, H=16, D=64
// R6: (1) GEMMs BK=32 -> BK=64 (half the barrier drains, 32 MFMA/barrier-pair,
// 32 KB LDS still 3 blocks/CU); (2) attn BQ=128 -> BQ=64 (1024 blocks,
// 3 blocks/CU, launch_bounds(256,3)) for latency hiding of the online softmax.
// Online softmax kept VERBATIM in math (known good, absmax 0.039).

#define LL 2048
#define EE 1024
#define HH 16
#define BL 4096   // B*L
#define KK 2048   // GEMM K (re||im)

typedef __attribute__((ext_vector_type(8))) short bf16x8;
typedef __attribute__((ext_vector_type(4))) float f32x4;
typedef unsigned short u16;

__device__ __forceinline__ u16 f2bf(float x) {
    unsigned u = __builtin_bit_cast(unsigned, x);
    u += 0x7fff + ((u >> 16) & 1);          // RNE
    return (u16)(u >> 16);
}

__device__ __forceinline__ void gl2lds16(const void* g, void* l) {
    __builtin_amdgcn_global_load_lds((const __attribute__((address_space(1))) void*)g,
                                     (__attribute__((address_space(3))) void*)l, 16, 0, 0);
}

// ---------------------------------------------------------------------------
// Merged fp32->bf16 conversion: 6 activation tensors, grid (4096, 6)
// ---------------------------------------------------------------------------
struct ConvXArgs { const float* src[6]; u16* dst[6]; };
__global__ void conv_x(ConvXArgs a) {
    const int z = blockIdx.y;
    int i = blockIdx.x * 256 + threadIdx.x;     // 1,048,576 float4 groups exactly
    float4 v = ((const float4*)a.src[z])[i];
    ushort4 o;
    o.x = f2bf(v.x); o.y = f2bf(v.y); o.z = f2bf(v.z); o.w = f2bf(v.w);
    ((ushort4*)a.dst[z])[i] = o;
}

// ---------------------------------------------------------------------------
// Merged W2 build: 4 weight pairs, grid (4096, 4)
// W2 bf16 [2048 n][2048 k]: n<1024: [Wr | -Wi] ; n>=1024: [Wi | Wr]
// ---------------------------------------------------------------------------
struct ConvWArgs { const float* wr[4]; const float* wi[4]; u16* w2[4]; };
__global__ void conv_w(ConvWArgs a) {
    const int z = blockIdx.y;
    int i = blockIdx.x * 256 + threadIdx.x;     // 2048*512 groups exactly
    int n = i >> 9, k = (i & 511) << 2;
    bool nh = n >= EE, kh = k >= EE;
    int nn = n & (EE - 1), kk = k & (EE - 1);
    const float* src = nh ? (kh ? a.wr[z] : a.wi[z]) : (kh ? a.wi[z] : a.wr[z]);
    float sgn = (!nh && kh) ? -1.0f : 1.0f;
    float4 v = *(const float4*)(src + nn * EE + kk);
    ushort4 o;
    o.x = f2bf(v.x * sgn); o.y = f2bf(v.y * sgn);
    o.z = f2bf(v.z * sgn); o.w = f2bf(v.w * sgn);
    *(ushort4*)(a.w2[z] + n * KK + k) = o;
}

// ---------------------------------------------------------------------------
// GEMM K-loop core, BK=64: As/Bs [128][64] u16 (16 KB each), XOR swizzle by
// row&7 over 8 16B-chunks/row. 2 barriers per 64-K step, 32 MFMA between.
// ---------------------------------------------------------------------------
#define GEMM_BK64_LOOP(Ar, Ai, B2)                                             \
    for (int k0 = 0; k0 < KK; k0 += 64) {                                      \
        const u16* Asrc = (k0 < EE) ? (Ar + k0) : (Ai + (k0 - EE));            \
        const u16* Bsrc = B2 + k0;                                             \
        __syncthreads();                                                       \
        {                                                                      \
            int rr = lane >> 3, cg = (lane & 7) ^ rr;                          \
            for (int t = 0; t < 4; t++) {                                      \
                int s = wave * 4 + t;                                          \
                int r0 = s * 8 + rr;                                           \
                gl2lds16(Asrc + (size_t)(m0 + r0) * EE + cg * 8, &As[s * 512]);\
                gl2lds16(Bsrc + (size_t)(n0 + r0) * KK + cg * 8, &Bs[s * 512]);\
            }                                                                  \
        }                                                                      \
        __syncthreads();                                                       \
        for (int ks2 = 0; ks2 < 2; ks2++) {                                    \
            bf16x8 a[4], b[4];                                                 \
            for (int t = 0; t < 4; t++) {                                      \
                int ra = wm + t * 16 + l16;                                    \
                a[t] = *(const bf16x8*)&As[ra * 64 + (((ks2 * 4 + quad) ^ (ra & 7)) << 3)]; \
                int rb = wn + t * 16 + l16;                                    \
                b[t] = *(const bf16x8*)&Bs[rb * 64 + (((ks2 * 4 + quad) ^ (rb & 7)) << 3)]; \
            }                                                                  \
            for (int i = 0; i < 4; i++)                                        \
                for (int j = 0; j < 4; j++)                                    \
                    acc[i][j] = __builtin_amdgcn_mfma_f32_16x16x32_bf16(a[i], b[j], acc[i][j], 0, 0, 0); \
        }                                                                      \
    }

// ---------------------------------------------------------------------------
// Merged Q/K/V projection GEMM: grid (16, 32, 3), z selects tensor.
// z=0 (Q) / z=1 (K): epilogue -> ws[bh][l][128] bf16 (Q scaled by oscale)
// z=2 (V):           epilogue -> ws[bh][128][2048] bf16 (transposed)
// ---------------------------------------------------------------------------
struct QKVArgs {
    const u16* Ar[3]; const u16* Ai[3]; const u16* B2[3];
    const float* br[3]; const float* bi[3];
    u16* out[3];
    float oscale[3];
};

__launch_bounds__(256, 3)
__global__ void gemm_qkv(QKVArgs args) {
    __shared__ __attribute__((aligned(16))) u16 As[128 * 64];
    __shared__ __attribute__((aligned(16))) u16 Bs[128 * 64];

    const int z = blockIdx.z;
    const u16* __restrict__ Ar = args.Ar[z];
    const u16* __restrict__ Ai = args.Ai[z];
    const u16* __restrict__ B2 = args.B2[z];

    const int tid = threadIdx.x, wave = tid >> 6, lane = tid & 63;
    const int quad = lane >> 4, l16 = lane & 15;
    const int m0 = blockIdx.y * 128, n0 = blockIdx.x * 128;
    const int wm = (wave >> 1) * 64, wn = (wave & 1) * 64;

    f32x4 acc[4][4] = {};

    GEMM_BK64_LOOP(Ar, Ai, B2)

    const float* __restrict__ br_ = args.br[z];
    const float* __restrict__ bi_ = args.bi[z];
    u16* __restrict__ out = args.out[z];
    const float oscale = args.oscale[z];

    for (int j = 0; j < 4; j++) {
        int gn = n0 + wn + j * 16 + l16;
        int ri = gn >> 10, e = gn & 1023;
        float bias = ri ? bi_[e] : br_[e];
        for (int i = 0; i < 4; i++) {
            int gmb = m0 + wm + i * 16 + quad * 4;
            for (int r = 0; r < 4; r++) {
                int gm = gmb + r;
                float v = (acc[i][j][r] + bias) * oscale;
                int b = gm >> 11, l = gm & 2047;
                int h = e >> 6, d = e & 63;
                if (z < 2)
                    out[((b * HH + h) * LL + l) * 128 + ri * 64 + d] = f2bf(v);
                else
                    out[((b * HH + h) * 128 + ri * 64 + d) * LL + l] = f2bf(v);
            }
        }
    }
}

// ---------------------------------------------------------------------------
// Output projection GEMM -> d_out fp32 [2][4096][1024]
// ---------------------------------------------------------------------------
__launch_bounds__(256, 2)
__global__ void gemm_oproj(const u16* __restrict__ Ar, const u16* __restrict__ Ai,
                           const u16* __restrict__ B2,
                           const float* __restrict__ br, const float* __restrict__ bi,
                           float* __restrict__ out)
{
    __shared__ __attribute__((aligned(16))) u16 As[128 * 64];
    __shared__ __attribute__((aligned(16))) u16 Bs[128 * 64];

    const int tid = threadIdx.x, wave = tid >> 6, lane = tid & 63;
    const int quad = lane >> 4, l16 = lane & 15;
    const int m0 = blockIdx.y * 128, n0 = blockIdx.x * 128;
    const int wm = (wave >> 1) * 64, wn = (wave & 1) * 64;

    f32x4 acc[4][4] = {};

    GEMM_BK64_LOOP(Ar, Ai, B2)

    for (int j = 0; j < 4; j++) {
        int gn = n0 + wn + j * 16 + l16;
        int ri = gn >> 10, e = gn & 1023;
        float bias = ri ? bi[e] : br[e];
        for (int i = 0; i < 4; i++) {
            int gmb = m0 + wm + i * 16 + quad * 4;
            for (int r = 0; r < 4; r++) {
                int gm = gmb + r;
                out[ri * (BL * EE) + gm * EE + e] = acc[i][j][r] + bias;
            }
        }
    }
}

// ---------------------------------------------------------------------------
// Flash attention, BQ=64 (grid 32x32, 3 blocks/CU): transposed-S, online
// softmax in log2 domain (math VERBATIM from the known-good R2 kernel, with
// the ntq dimension dropped: each wave owns 16 q rows).
// q_ws/k_ws: bf16 [bh][l][128] (Q pre-scaled by 0.125*log2e); v_ws: [bh][128][2048]
// ---------------------------------------------------------------------------
__launch_bounds__(256, 3)
__global__ void attn(const u16* __restrict__ q_ws, const u16* __restrict__ k_ws,
                     const u16* __restrict__ v_ws,
                     u16* __restrict__ o_r, u16* __restrict__ o_i)
{
    __shared__ __attribute__((aligned(16))) u16 kbuf[2][64 * 128];  // 2x16 KB
    __shared__ __attribute__((aligned(16))) u16 vbuf[128 * 64];     // 16 KB
    __shared__ __attribute__((aligned(16))) float red_sh[4][16];

    const int tid = threadIdx.x, wave = tid >> 6, lane = tid & 63;
    const int quad = lane >> 4, l16 = lane & 15;
    const int q0 = blockIdx.x * 64, bh = blockIdx.y;

    // Q fragments (B-operand layout: row = l16, k = quad*8+j); wave owns 16 q rows
    bf16x8 qf[4];
    {
        const u16* qp = q_ws + (size_t)(bh * LL + q0 + wave * 16 + l16) * 128 + quad * 8;
        for (int ks = 0; ks < 4; ks++)
            qf[ks] = *(const bf16x8*)(qp + ks * 32);
    }

    auto stage_k = [&](int nb, int kv0) {
        for (int t = 0; t < 4; t++) {
            int s = wave * 4 + t;
            int row = s * 4 + (lane >> 4);
            int cg = (lane & 15) ^ (row & 15);
            gl2lds16(k_ws + (size_t)(bh * LL + kv0 + row) * 128 + cg * 8, &kbuf[nb][s * 512]);
        }
    };
    auto stage_v = [&](int kv0) {
        for (int t = 0; t < 4; t++) {
            int s = wave * 4 + t;
            int row = s * 8 + (lane >> 3);
            int cg = (lane & 7) ^ (row & 7);
            gl2lds16(v_ws + (size_t)(bh * 128 + row) * LL + kv0 + cg * 8, &vbuf[s * 512]);
        }
    };

    stage_k(0, 0);
    stage_v(0);
    stage_k(1, 64);
    __syncthreads();

    f32x4 oacc[8] = {};
    float m_st = -__builtin_inff();
    float l_st = 0.f;

    for (int N = 0; N < 32; N++) {
        const int cur = N & 1;
        u16* K = kbuf[cur];

        // ---- S^T[64 kv][16 q] = K . Q^T ----
        f32x4 s[4] = {};
        for (int ks = 0; ks < 4; ks++) {
            bf16x8 kf[4];
            for (int mt = 0; mt < 4; mt++) {
                int row = mt * 16 + l16;
                int cl = (ks * 4 + quad) ^ (row & 15);
                kf[mt] = *(const bf16x8*)&K[row * 128 + cl * 8];
            }
            for (int mt = 0; mt < 4; mt++)
                s[mt] = __builtin_amdgcn_mfma_f32_16x16x32_bf16(kf[mt], qf[ks], s[mt], 0, 0, 0);
        }

        // ---- online softmax (log2 domain); q = l16, kv = mt*16+quad*4+r ----
        bool changed = false;
        float alpha;
        {
            float mx = -__builtin_inff();
            for (int mt = 0; mt < 4; mt++)
                for (int r = 0; r < 4; r++)
                    mx = fmaxf(mx, s[mt][r]);
            mx = fmaxf(mx, __shfl_xor(mx, 16, 64));
            mx = fmaxf(mx, __shfl_xor(mx, 32, 64));
            float mnew = fmaxf(m_st, mx);
            changed = (mnew != m_st);
            alpha = __builtin_amdgcn_exp2f(m_st - mnew);
            m_st = mnew;
            float sum = 0.f;
            for (int mt = 0; mt < 4; mt++)
                for (int r = 0; r < 4; r++) {
                    float p = __builtin_amdgcn_exp2f(s[mt][r] - mnew);
                    s[mt][r] = p;
                    sum += p;
                }
            sum += __shfl_xor(sum, 16, 64);
            sum += __shfl_xor(sum, 32, 64);
            l_st = l_st * alpha + sum;
            if (quad == 0) red_sh[wave][l16] = alpha;
        }
        __syncthreads();   // barrier A: K[cur] reads done; drains prev async loads

        // ---- P (A-layout [16 q][64 kv]) into own slice of kbuf[cur] ----
        u16* P = kbuf[cur] + wave * 1024;
        for (int mt = 0; mt < 4; mt++) {
            int q = l16;
            int cg = mt * 2 + (quad >> 1);
            int cl = cg ^ (q & 7);
            ushort4 pk;
            pk.x = f2bf(s[mt][0]); pk.y = f2bf(s[mt][1]);
            pk.z = f2bf(s[mt][2]); pk.w = f2bf(s[mt][3]);
            *(ushort4*)&P[q * 64 + cl * 8 + (quad & 1) * 4] = pk;
        }

        // ---- O rescale (skip when running max unchanged wave-wide) ----
        if (__any(changed)) {
            f32x4 av = *(const f32x4*)&red_sh[wave][quad * 4];
            for (int nt = 0; nt < 8; nt++)
                oacc[nt] *= av;
        }

        // ---- O += P @ V ----
        for (int ks = 0; ks < 2; ks++) {
            int clp = (ks * 4 + quad) ^ (l16 & 7);
            bf16x8 pf = *(const bf16x8*)&P[l16 * 64 + clp * 8];
            for (int nt = 0; nt < 8; nt++) {
                int row = nt * 16 + l16;
                int cl = (ks * 4 + quad) ^ (row & 7);
                bf16x8 vf = *(const bf16x8*)&vbuf[row * 64 + cl * 8];
                oacc[nt] = __builtin_amdgcn_mfma_f32_16x16x32_bf16(pf, vf, oacc[nt], 0, 0, 0);
            }
        }
        __syncthreads();   // barrier B: PV done everywhere; P dead, vbuf free

        if (N + 2 < 32) stage_k(cur, (N + 2) * 64);   // into region P occupied
        if (N + 1 < 32) stage_v((N + 1) * 64);
    }

    // ---- epilogue: O /= l, write bf16 o_r/o_i [4096][1024] ----
    if (quad == 0) red_sh[wave][l16] = l_st;
    __syncthreads();
    f32x4 lv = *(const f32x4*)&red_sh[wave][quad * 4];
    f32x4 inv;
    for (int r = 0; r < 4; r++) inv[r] = 1.0f / lv[r];
    const int b = bh >> 4, h = bh & 15;
    for (int nt = 0; nt < 8; nt++) {
        int d2 = nt * 16 + l16;
        u16* op = (d2 < 64) ? o_r : o_i;
        int col = h * 64 + (d2 & 63);
        for (int r = 0; r < 4; r++) {
            int l = q0 + wave * 16 + quad * 4 + r;
            op[(size_t)(b * LL + l) * EE + col] = f2bf(oacc[nt][r] * inv[r]);
        }
    }
}

// ---------------------------------------------------------------------------
extern "C" void kernel_launch(void* const* d_in, const int* in_sizes, int n_in,
                              void* d_out, int out_size, void* d_ws, size_t ws_size,
                              hipStream_t stream) {
    const float* bq_r = (const float*)d_in[8];
    const float* bq_i = (const float*)d_in[9];
    const float* bk_r = (const float*)d_in[12];
    const float* bk_i = (const float*)d_in[13];
    const float* bv_r = (const float*)d_in[16];
    const float* bv_i = (const float*)d_in[17];
    const float* bo_r = (const float*)d_in[20];
    const float* bo_i = (const float*)d_in[21];

    u16* ws = (u16*)d_ws;
    const size_t XN = 4194304;          // 4096*1024 elements (= 2048*2048)
    u16* xqr = ws;            u16* xqi = xqr + XN;
    u16* xkr = xqi + XN;      u16* xki = xkr + XN;
    u16* xvr = xki + XN;      u16* xvi = xvr + XN;
    u16* w2q = xvi + XN;
    u16* w2k = w2q + XN;
    u16* w2v = w2k + XN;
    u16* w2o = w2v + XN;
    u16* q_ws = w2o + XN;               // 32*2048*128 = 8,388,608
    u16* k_ws = q_ws + 8388608;
    u16* v_ws = k_ws + 8388608;
    u16* o_r = xqr;                     // X regions dead after QKV GEMMs
    u16* o_i = xqr + XN;

    dim3 blk(256);

    ConvXArgs cx;
    cx.src[0] = (const float*)d_in[0]; cx.dst[0] = xqr;
    cx.src[1] = (const float*)d_in[1]; cx.dst[1] = xqi;
    cx.src[2] = (const float*)d_in[2]; cx.dst[2] = xkr;
    cx.src[3] = (const float*)d_in[3]; cx.dst[3] = xki;
    cx.src[4] = (const float*)d_in[4]; cx.dst[4] = xvr;
    cx.src[5] = (const float*)d_in[5]; cx.dst[5] = xvi;
    conv_x<<<dim3(4096, 6), blk, 0, stream>>>(cx);

    ConvWArgs cw;
    cw.wr[0] = (const float*)d_in[6];  cw.wi[0] = (const float*)d_in[7];  cw.w2[0] = w2q;
    cw.wr[1] = (const float*)d_in[10]; cw.wi[1] = (const float*)d_in[11]; cw.w2[1] = w2k;
    cw.wr[2] = (const float*)d_in[14]; cw.wi[2] = (const float*)d_in[15]; cw.w2[2] = w2v;
    cw.wr[3] = (const float*)d_in[18]; cw.wi[3] = (const float*)d_in[19]; cw.w2[3] = w2o;
    conv_w<<<dim3(4096, 4), blk, 0, stream>>>(cw);

    const float QSCALE = 0.125f * 1.44269504088896f;   // 1/sqrt(D) * log2(e)
    QKVArgs qa;
    qa.Ar[0] = xqr; qa.Ai[0] = xqi; qa.B2[0] = w2q; qa.br[0] = bq_r; qa.bi[0] = bq_i; qa.out[0] = q_ws; qa.oscale[0] = QSCALE;
    qa.Ar[1] = xkr; qa.Ai[1] = xki; qa.B2[1] = w2k; qa.br[1] = bk_r; qa.bi[1] = bk_i; qa.out[1] = k_ws; qa.oscale[1] = 1.0f;
    qa.Ar[2] = xvr; qa.Ai[2] = xvi; qa.B2[2] = w2v; qa.br[2] = bv_r; qa.bi[2] = bv_i; qa.out[2] = v_ws; qa.oscale[2] = 1.0f;
    gemm_qkv<<<dim3(16, 32, 3), blk, 0, stream>>>(qa);

    attn<<<dim3(32, 32), blk, 0, stream>>>(q_ws, k_ws, v_ws, o_r, o_i);

    gemm_oproj<<<dim3(16, 32), blk, 0, stream>>>(o_r, o_i, w2o, bo_r, bo_i, (float*)d_out);
}